// Round 13
// baseline (62.044 us; speedup 1.0000x reference)
//
#include <hip/hip_runtime.h>
#include <hip/hip_bf16.h>
#include <math.h>

#define EPSF 1e-8f

constexpr int N_OBJ  = 8192;
constexpr int M_SR   = 4096;
constexpr int N_FACE = 2048;

constexpr int PPB  = 16;             // points per block
constexpr int NBLK = N_OBJ / PPB;    // 512
constexpr int FT   = 256;            // faces per LDS tile
constexpr int NT   = N_FACE / FT;    // 8

// ws: pensum[512] floats (fully overwritten each call)

__global__ __launch_bounds__(256) void fused(
    const float* __restrict__ obj, const float* __restrict__ srp,
    const float* __restrict__ verts, const int* __restrict__ faces,
    const float* __restrict__ fnorm, float* __restrict__ out,
    float* __restrict__ pensum)
{
    __shared__ float fds[2][FT][16];   // 32 KB, double-buffered face consts
    __shared__ float ptd[PPB][9];      // point records (padded rows)
    __shared__ int   scnt[16][17];     // per-sub hit counts

    const int tid   = threadIdx.x;
    const int pbase = blockIdx.x * PPB;

    // ---- face tile staging (one face per thread) ----
    auto stage = [&](int buf, int t8) {
        const int f  = t8 * FT + tid;
        const int i0 = faces[3 * f + 0], i1 = faces[3 * f + 1], i2 = faces[3 * f + 2];
        const float ax = verts[3 * i0 + 0], ay = verts[3 * i0 + 1], az = verts[3 * i0 + 2];
        const float bx = verts[3 * i1 + 0], by = verts[3 * i1 + 1], bz = verts[3 * i1 + 2];
        const float cx = verts[3 * i2 + 0], cy = verts[3 * i2 + 1], cz = verts[3 * i2 + 2];
        const float fx = fnorm[3 * f + 0], fy = fnorm[3 * f + 1], fz = fnorm[3 * f + 2];
        const float nf = fx * ax + fy * ay + fz * az;

        const float e0x = bx - ax, e0y = by - ay, e0z = bz - az;
        const float g0x = fy * e0z - fz * e0y, g0y = fz * e0x - fx * e0z, g0z = fx * e0y - fy * e0x;
        const float h0  = g0x * ax + g0y * ay + g0z * az;
        const float e1x = cx - bx, e1y = cy - by, e1z = cz - bz;
        const float g1x = fy * e1z - fz * e1y, g1y = fz * e1x - fx * e1z, g1z = fx * e1y - fy * e1x;
        const float h1  = g1x * bx + g1y * by + g1z * bz;
        const float e2x = ax - cx, e2y = ay - cy, e2z = az - cz;
        const float g2x = fy * e2z - fz * e2y, g2y = fz * e2x - fx * e2z, g2z = fx * e2y - fy * e2x;
        const float h2  = g2x * cx + g2y * cy + g2z * cz;

        float* o = &fds[buf][tid][0];
        *(float4*)(o + 0)  = make_float4(fx, fy, fz, nf);
        *(float4*)(o + 4)  = make_float4(g0x, g0y, g0z, h0);
        *(float4*)(o + 8)  = make_float4(g1x, g1y, g1z, h1);
        *(float4*)(o + 12) = make_float4(g2x, g2y, g2z, h2);
    };

    stage(0, 0);    // overlap tile-0 staging with phase A

    // ================= Phase A: NN (16 subs per point, direct global reads) =================
    {
        const int ptA  = tid >> 4;
        const int subA = tid & 15;
        const int p    = pbase + ptA;
        const float ox = obj[3 * p], oy = obj[3 * p + 1], oz = obj[3 * p + 2];

        float best = 3.4e38f;
        int   bi   = 0;
#pragma unroll 4
        for (int j = 0; j < M_SR / 16 - 1; ++j) {
            const int idx = j * 16 + subA;
            float4 v = *(const float4*)(srp + 3 * idx);   // overlapping, dword-aligned
            float dx = ox - v.x, dy = oy - v.y, dz = oz - v.z;
            float d2 = dx * dx + dy * dy + dz * dz;
            if (d2 < best) { best = d2; bi = idx; }
        }
        {   // last group: scalar loads (avoid 4B overrun at sr tail)
            const int idx = (M_SR / 16 - 1) * 16 + subA;
            float sx = srp[3 * idx], sy = srp[3 * idx + 1], sz = srp[3 * idx + 2];
            float dx = ox - sx, dy = oy - sy, dz = oz - sz;
            float d2 = dx * dx + dy * dy + dz * dz;
            if (d2 < best) { best = d2; bi = idx; }
        }
        // reduce across the 16 subs (same wave), first-min tie-break by index
#pragma unroll
        for (int off = 1; off < 16; off <<= 1) {
            float od = __shfl_xor(best, off);
            int   oi = __shfl_xor(bi, off);
            if (od < best || (od == best && oi < bi)) { best = od; bi = oi; }
        }
        if (subA == 0) {
            float dx = srp[3 * bi] - ox, dy = srp[3 * bi + 1] - oy, dz = srp[3 * bi + 2] - oz;
            ptd[ptA][0] = ox; ptd[ptA][1] = oy; ptd[ptA][2] = oz;
            ptd[ptA][3] = dx; ptd[ptA][4] = dy; ptd[ptA][5] = dz;
            ptd[ptA][6] = best;
            out[1 + p] = 2.0f / (1.0f + expf(100.0f * sqrtf(best + EPSF)));
        }
    }
    __syncthreads();   // ptd ready, tile-0 staged

    // ================= Phase B: ray-triangle parity over 8 dbuf tiles =================
    const int subB = tid >> 4;    // face sub-slice 0..15
    const int ptB  = tid & 15;    // point 0..15
    const float ox = ptd[ptB][0], oy = ptd[ptB][1], oz = ptd[ptB][2];
    const float dx = ptd[ptB][3], dy = ptd[ptB][4], dz = ptd[ptB][5];

    int cnt = 0;
    for (int t8 = 0; t8 < NT; ++t8) {
        if (t8 < NT - 1) stage((t8 + 1) & 1, t8 + 1);
        const float (*__restrict__ F)[16] = fds[t8 & 1];
#pragma unroll 4
        for (int k = 0; k < 16; ++k) {
            const int fl = k * 16 + subB;          // sub-interleaved: 2-way banks (free)
            const float* c = &F[fl][0];
            float4 q0 = *(const float4*)(c + 0);
            float den = q0.x * dx + q0.y * dy + q0.z * dz;
            float num = q0.w - (q0.x * ox + q0.y * oy + q0.z * oz);
            float Px  = den * ox + num * dx;
            float Py  = den * oy + num * dy;
            float Pz  = den * oz + num * dz;
            bool pos = den >= 0.0f;

            float4 q1 = *(const float4*)(c + 4);
            bool ok0 = ((q1.x * Px + q1.y * Py + q1.z * Pz - den * q1.w) >= 0.0f) == pos;
            float4 q2 = *(const float4*)(c + 8);
            bool ok1 = ((q2.x * Px + q2.y * Py + q2.z * Pz - den * q2.w) >= 0.0f) == pos;
            float4 q3 = *(const float4*)(c + 12);
            bool ok2 = ((q3.x * Px + q3.y * Py + q3.z * Pz - den * q3.w) >= 0.0f) == pos;

            bool tok = (num >= 0.0f) == pos;
            bool aok = fabsf(den) >= EPSF;
            cnt += (ok0 & ok1 & ok2 & tok & aok) ? 1 : 0;
        }
        __syncthreads();   // next buffer staged; current reads done
    }

    // ================= Phase C: in-block parity + pen partial =================
    scnt[subB][ptB] = cnt;
    __syncthreads();
    float s = 0.0f;
    if (tid < PPB) {
        int tot = 0;
#pragma unroll
        for (int sb = 0; sb < 16; ++sb) tot += scnt[sb][tid];
        s = (tot & 1) ? ptd[tid][6] : 0.0f;
    }
    // threads 0..15 live in wave 0: reduce lanes 0..15
#pragma unroll
    for (int off = 1; off < 16; off <<= 1) s += __shfl_xor(s, off);
    if (tid == 0) pensum[blockIdx.x] = s;
}

// ================= FIN: sum 512 partials -> sqrt -> out[0] =================
__global__ __launch_bounds__(64) void fin(
    const float* __restrict__ pensum, float* __restrict__ out)
{
    const int l = threadIdx.x;
    const float4* __restrict__ p4 = (const float4*)pensum;   // 128 float4
    float4 a = p4[2 * l], b = p4[2 * l + 1];
    float s = a.x + a.y + a.z + a.w + b.x + b.y + b.z + b.w;
#pragma unroll
    for (int off = 1; off < 64; off <<= 1) s += __shfl_xor(s, off);
    if (l == 0) out[0] = sqrtf(s);
}

extern "C" void kernel_launch(void* const* d_in, const int* in_sizes, int n_in,
                              void* d_out, int out_size, void* d_ws, size_t ws_size,
                              hipStream_t stream)
{
    const float* obj   = (const float*)d_in[0];
    const float* srp   = (const float*)d_in[1];
    const float* verts = (const float*)d_in[2];
    const int*   faces = (const int*)d_in[3];
    const float* fnorm = (const float*)d_in[4];
    float*       out   = (float*)d_out;
    float*       pensum = (float*)d_ws;

    fused<<<NBLK, 256, 0, stream>>>(obj, srp, verts, faces, fnorm, out, pensum);
    fin<<<1, 64, 0, stream>>>(pensum, out);
}